// Round 3
// baseline (76.825 us; speedup 1.0000x reference)
//
#include <hip/hip_runtime.h>

#define DM    1024
#define NTOK  32768   // B*S
#define NRED  16384
#define NSAVE 16384
#define MMAX  16384   // max compacted rows

typedef __attribute__((ext_vector_type(8))) short bf16x8;
typedef __attribute__((ext_vector_type(4))) float f32x4;

__device__ __forceinline__ ushort f2bf(float f) {
    union { float f; unsigned u; } v; v.f = f;
    unsigned r = (v.u + 0x7FFF + ((v.u >> 16) & 1)) >> 16;   // RNE
    return (ushort)r;
}
__device__ __forceinline__ float bf2f(ushort u) {
    union { unsigned u; float f; } v; v.u = ((unsigned)u) << 16;
    return v.f;
}

// ---------------------------------------------------------------------------
// setup: W -> bf16, zero cnt/need, counter=0   (inv needs no init: every inv
// read in out_kernel is guarded by need&&cnt>0, which compact always writes)
// grid 1024 x 256 covers the 262144 float4 of W; first 32768 threads also init.
// ---------------------------------------------------------------------------
__global__ __launch_bounds__(256) void setup_kernel(const float* __restrict__ W,
                                                    ushort* __restrict__ Wb,
                                                    int* __restrict__ cnt,
                                                    int* __restrict__ need,
                                                    int* __restrict__ counter) {
    int t = blockIdx.x * 256 + threadIdx.x;
    float4 v = ((const float4*)W)[t];
    ushort4 o;
    o.x = f2bf(v.x); o.y = f2bf(v.y); o.z = f2bf(v.z); o.w = f2bf(v.w);
    ((ushort4*)Wb)[t] = o;
    if (t < NTOK) { cnt[t] = 0; need[t] = 0; }
    if (t == 0) *counter = 0;
}

// ---------------------------------------------------------------------------
__global__ __launch_bounds__(256) void prep_kernel(const int* __restrict__ red,
                                                   const int* __restrict__ sav,
                                                   int* __restrict__ cnt,
                                                   int* __restrict__ need) {
    int j = blockIdx.x * 256 + threadIdx.x;
    if (j >= NRED) return;
    atomicAdd(&cnt[red[j]], 1);
    int s = sav[j];
    if (s > 0) need[s - 1] = 1;
}

// ---------------------------------------------------------------------------
__global__ __launch_bounds__(256) void compact_kernel(const int* __restrict__ cnt,
                                                      const int* __restrict__ need,
                                                      int* __restrict__ inv,
                                                      int* __restrict__ list,
                                                      int* __restrict__ counter) {
    int t = blockIdx.x * 256 + threadIdx.x;
    if (t >= NTOK) return;
    if (need[t] && cnt[t] > 0) {
        int pos = atomicAdd(counter, 1);
        inv[t] = pos;
        list[pos] = t;
    }
}

// ---------------------------------------------------------------------------
// convx: gather + fp32->bf16 convert the compacted rows: Xb[r] = bf16(X[list[r]])
// grid-stride over M rows; one row per block-iter (256 thr x float4).
// ---------------------------------------------------------------------------
__global__ __launch_bounds__(256) void convx_kernel(const float* __restrict__ X,
                                                    const int* __restrict__ list,
                                                    const int* __restrict__ counter,
                                                    ushort* __restrict__ Xb) {
    const int M = *counter;
    for (int r = blockIdx.x; r < M; r += gridDim.x) {
        int src = list[r];
        float4 v = ((const float4*)(X + (size_t)src * DM))[threadIdx.x];
        ushort4 o;
        o.x = f2bf(v.x); o.y = f2bf(v.y); o.z = f2bf(v.z); o.w = f2bf(v.w);
        ((ushort4*)(Xb + (size_t)r * DM))[threadIdx.x] = o;
    }
}

// ---------------------------------------------------------------------------
// bf16 MFMA GEMM (m97 structure): Tb[m,n] = bf16( sum_k Xb[m,k] * Wb[n,k] )
// BM=BN=128, BK=32; 256 thr = 4 waves, wave tile 64x64 = 4x4 frags 16x16x32.
// Both operands staged via global_load_lds(16) with PRE-SWIZZLED source
// (16B slot ^= (row>>1)&3) so linear LDS dest lands swizzled (rule #21);
// ds_read_b128 then 2-way bank aliasing = free (m136).
// grid x = m-blocks (early-exit on M), y = n-blocks: linear id % 8 = mblk % 8
// -> each XCD keeps its A band + all of Wb L2-resident (T1 mechanism).
// ---------------------------------------------------------------------------
#define BM 128
#define BN 128
#define BK 32

__global__ __launch_bounds__(256) void gemm_kernel(const ushort* __restrict__ Xb,
                                                   const ushort* __restrict__ Wb,
                                                   const int* __restrict__ counter,
                                                   ushort* __restrict__ Tb) {
    const int M = *counter;
    const int m0 = blockIdx.x * BM;
    if (m0 >= M) return;
    const int n0 = blockIdx.y * BN;

    __shared__ ushort As[BM * BK];   // 8 KB, swizzled
    __shared__ ushort Bs[BN * BK];   // 8 KB, swizzled

    const int tid  = threadIdx.x;
    const int lane = tid & 63;
    const int wid  = tid >> 6;
    const int wr   = wid >> 1;       // 0..1 (64-row band)
    const int wc   = wid & 1;        // 0..1 (64-col band)
    const int kgrp = lane >> 4;      // 0..3
    const int r16  = lane & 15;

    // staging geometry: thread covers (local row = tid>>2, slot = tid&3);
    // issue 0 -> local rows 0..63, issue 1 -> local rows 64..127.
    const int srow  = tid >> 2;
    const int sslot = tid & 3;
    const int sw0 = (sslot ^ ((srow >> 1) & 3)) * 8;          // swizzled k-off
    const int sw1 = (sslot ^ (((64 + srow) >> 1) & 3)) * 8;
    const ushort* aptr0 = Xb + (size_t)(m0 + srow) * DM + sw0;
    const ushort* aptr1 = Xb + (size_t)(m0 + 64 + srow) * DM + sw1;
    const ushort* bptr0 = Wb + (size_t)(n0 + srow) * DM + sw0;
    const ushort* bptr1 = Wb + (size_t)(n0 + 64 + srow) * DM + sw1;
    char* AsD = (char*)As + wid * 1024;   // wave-uniform linear dest
    char* BsD = (char*)Bs + wid * 1024;

    // fragment read offsets (same swizzle, local rows)
    int aoff[4], boff[4];
#pragma unroll
    for (int fm = 0; fm < 4; ++fm) {
        int row = wr * 64 + fm * 16 + r16;
        aoff[fm] = row * BK + ((kgrp ^ ((row >> 1) & 3)) * 8);
    }
#pragma unroll
    for (int fn = 0; fn < 4; ++fn) {
        int row = wc * 64 + fn * 16 + r16;
        boff[fn] = row * BK + ((kgrp ^ ((row >> 1) & 3)) * 8);
    }

    f32x4 acc[4][4] = {};

    for (int k0 = 0; k0 < DM; k0 += BK) {
        __syncthreads();   // previous iteration's ds_reads complete
        __builtin_amdgcn_global_load_lds(
            (const __attribute__((address_space(1))) unsigned*)(aptr0 + k0),
            (__attribute__((address_space(3))) unsigned*)(AsD), 16, 0, 0);
        __builtin_amdgcn_global_load_lds(
            (const __attribute__((address_space(1))) unsigned*)(aptr1 + k0),
            (__attribute__((address_space(3))) unsigned*)(AsD + 4096), 16, 0, 0);
        __builtin_amdgcn_global_load_lds(
            (const __attribute__((address_space(1))) unsigned*)(bptr0 + k0),
            (__attribute__((address_space(3))) unsigned*)(BsD), 16, 0, 0);
        __builtin_amdgcn_global_load_lds(
            (const __attribute__((address_space(1))) unsigned*)(bptr1 + k0),
            (__attribute__((address_space(3))) unsigned*)(BsD + 4096), 16, 0, 0);
        __syncthreads();   // drains vmcnt -> LDS tiles ready

        bf16x8 af[4], bf[4];
#pragma unroll
        for (int i = 0; i < 4; ++i) af[i] = *(const bf16x8*)(As + aoff[i]);
#pragma unroll
        for (int j = 0; j < 4; ++j) bf[j] = *(const bf16x8*)(Bs + boff[j]);
#pragma unroll
        for (int i = 0; i < 4; ++i)
#pragma unroll
            for (int j = 0; j < 4; ++j)
                acc[i][j] = __builtin_amdgcn_mfma_f32_16x16x32_bf16(af[i], bf[j], acc[i][j], 0, 0, 0);
    }

    // C/D layout: col = lane&15, row = (lane>>4)*4 + reg  [m89]
#pragma unroll
    for (int fm = 0; fm < 4; ++fm) {
        int mbase = m0 + wr * 64 + fm * 16 + kgrp * 4;
#pragma unroll
        for (int fn = 0; fn < 4; ++fn) {
            int n = n0 + wc * 64 + fn * 16 + r16;
#pragma unroll
            for (int r = 0; r < 4; ++r) {
                int m = mbase + r;
                if (m < M) Tb[(size_t)m * DM + n] = f2bf(acc[fm][fn][r]);
            }
        }
    }
}

// ---------------------------------------------------------------------------
// epilogue: out[r] = x[s] + cnt[s-1] * Tb[inv[s-1]]
// ---------------------------------------------------------------------------
__global__ __launch_bounds__(256) void out_kernel(const float* __restrict__ X,
                                                  const ushort* __restrict__ Tb,
                                                  const int* __restrict__ sav,
                                                  const int* __restrict__ cnt,
                                                  const int* __restrict__ inv,
                                                  float* __restrict__ out) {
    int r = blockIdx.x;
    int d = threadIdx.x;                 // float4 lane, 0..255
    int s = sav[r];
    const float4* xr = (const float4*)(X + (size_t)s * DM);
    float4 v = xr[d];
    if (s > 0) {
        int t = s - 1;
        int c = cnt[t];
        if (c > 0) {
            float fc = (float)c;
            const ushort4* tr = (const ushort4*)(Tb + (size_t)inv[t] * DM);
            ushort4 w = tr[d];
            v.x += fc * bf2f(w.x); v.y += fc * bf2f(w.y);
            v.z += fc * bf2f(w.z); v.w += fc * bf2f(w.w);
        }
    }
    ((float4*)out)[(size_t)r * (DM / 4) + d] = v;
}

// ---------------------------------------------------------------------------
extern "C" void kernel_launch(void* const* d_in, const int* in_sizes, int n_in,
                              void* d_out, int out_size, void* d_ws, size_t ws_size,
                              hipStream_t stream) {
    const float* X   = (const float*)d_in[0];
    const float* W   = (const float*)d_in[1];
    const int*   sav = (const int*)d_in[2];   // ids_to_save
    const int*   red = (const int*)d_in[3];   // ids_to_reduce
    float* out = (float*)d_out;

    char* ws = (char*)d_ws;
    int* counter = (int*)ws;                  // 64 ints
    int* cnt  = counter + 64;                 // 32768
    int* need = cnt + NTOK;                   // 32768
    int* inv  = need + NTOK;                  // 32768
    int* list = inv + NTOK;                   // 16384  (ends < 512 KB)
    ushort* Wb = (ushort*)(ws + (1 << 19));   // 2 MB bf16 W
    ushort* Xb = (ushort*)(ws + (4 << 20));   // 32 MB bf16 compacted X rows
    ushort* Tb = (ushort*)(ws + (36u << 20)); // 32 MB bf16 T   (total 68 MB; ws = 512 MB)

    setup_kernel<<<DM * DM / 4 / 256, 256, 0, stream>>>(W, Wb, cnt, need, counter);
    prep_kernel<<<NRED / 256, 256, 0, stream>>>(red, sav, cnt, need);
    compact_kernel<<<NTOK / 256, 256, 0, stream>>>(cnt, need, inv, list, counter);
    convx_kernel<<<2048, 256, 0, stream>>>(X, list, counter, Xb);

    dim3 ggrid(MMAX / BM, DM / BN);           // x = m-blocks (128, early-exit), y = n (8)
    gemm_kernel<<<ggrid, 256, 0, stream>>>(Xb, Wb, counter, Tb);

    out_kernel<<<NSAVE, 256, 0, stream>>>(X, Tb, sav, cnt, inv, out);
}

// Round 4
// 73.692 us; speedup vs baseline: 1.0425x; 1.0425x over previous
//
#include <hip/hip_runtime.h>

#define DM    1024
#define NTOK  32768   // B*S
#define NRED  16384
#define NSAVE 16384
#define MMAX  16384   // max compacted rows

typedef __attribute__((ext_vector_type(8))) short bf16x8;
typedef __attribute__((ext_vector_type(4))) float f32x4;

__device__ __forceinline__ ushort f2bf(float f) {
    union { float f; unsigned u; } v; v.f = f;
    unsigned r = (v.u + 0x7FFF + ((v.u >> 16) & 1)) >> 16;   // RNE
    return (ushort)r;
}
__device__ __forceinline__ float bf2f(ushort u) {
    union { unsigned u; float f; } v; v.u = ((unsigned)u) << 16;
    return v.f;
}

// ---------------------------------------------------------------------------
// setup: W -> bf16, zero cnt/need, counter=0
// ---------------------------------------------------------------------------
__global__ __launch_bounds__(256) void setup_kernel(const float* __restrict__ W,
                                                    ushort* __restrict__ Wb,
                                                    int* __restrict__ cnt,
                                                    int* __restrict__ need,
                                                    int* __restrict__ counter) {
    int t = blockIdx.x * 256 + threadIdx.x;
    float4 v = ((const float4*)W)[t];
    ushort4 o;
    o.x = f2bf(v.x); o.y = f2bf(v.y); o.z = f2bf(v.z); o.w = f2bf(v.w);
    ((ushort4*)Wb)[t] = o;
    if (t < NTOK) { cnt[t] = 0; need[t] = 0; }
    if (t == 0) *counter = 0;
}

// ---------------------------------------------------------------------------
__global__ __launch_bounds__(256) void prep_kernel(const int* __restrict__ red,
                                                   const int* __restrict__ sav,
                                                   int* __restrict__ cnt,
                                                   int* __restrict__ need) {
    int j = blockIdx.x * 256 + threadIdx.x;
    if (j >= NRED) return;
    atomicAdd(&cnt[red[j]], 1);
    int s = sav[j];
    if (s > 0) need[s - 1] = 1;
}

// ---------------------------------------------------------------------------
__global__ __launch_bounds__(256) void compact_kernel(const int* __restrict__ cnt,
                                                      const int* __restrict__ need,
                                                      int* __restrict__ inv,
                                                      int* __restrict__ list,
                                                      int* __restrict__ counter) {
    int t = blockIdx.x * 256 + threadIdx.x;
    if (t >= NTOK) return;
    if (need[t] && cnt[t] > 0) {
        int pos = atomicAdd(counter, 1);
        inv[t] = pos;
        list[pos] = t;
    }
}

// ---------------------------------------------------------------------------
// convx: gather + fp32->bf16 convert compacted rows: Xb[r] = bf16(X[list[r]])
// ---------------------------------------------------------------------------
__global__ __launch_bounds__(256) void convx_kernel(const float* __restrict__ X,
                                                    const int* __restrict__ list,
                                                    const int* __restrict__ counter,
                                                    ushort* __restrict__ Xb) {
    const int M = *counter;
    for (int r = blockIdx.x; r < M; r += gridDim.x) {
        int src = list[r];
        float4 v = ((const float4*)(X + (size_t)src * DM))[threadIdx.x];
        ushort4 o;
        o.x = f2bf(v.x); o.y = f2bf(v.y); o.z = f2bf(v.z); o.w = f2bf(v.w);
        ((ushort4*)(Xb + (size_t)r * DM))[threadIdx.x] = o;
    }
}

// ---------------------------------------------------------------------------
// Split-K-in-wg bf16 MFMA GEMM: Tb[m,n] = bf16( sum_k Xb[m,k] * Wb[n,k] )
// Tile 64x64, BK=128, 4 waves; wave w owns k-slice [w*256, w*256+256).
// Per K-step: stage A[64][128] + B[64][128] (32 KB) cooperatively via
// global_load_lds(16) with pre-swizzled SOURCE (chunk ^= row&7 on 16B chunks
// of the 256B row -> conflict-free ds_read_b128); wave w reads chunks
// w*4..w*4+3 only (no cross-wave LDS re-reads). Counted vmcnt(8) + raw
// s_barrier keeps next-buf loads in flight (T4). Epilogue: 4-way fp32
// partial combine through LDS (reuses the 64 KB staging buffer).
// Grid x=mblk: all 16 nblks of an m-band land on one XCD (linear%8=x%8).
// ---------------------------------------------------------------------------
__global__ __launch_bounds__(256) void gemm_kernel(const ushort* __restrict__ Xb,
                                                   const ushort* __restrict__ Wb,
                                                   const int* __restrict__ counter,
                                                   ushort* __restrict__ Tb) {
    const int M = *counter;
    const int m0 = blockIdx.x * 64;
    if (m0 >= M) return;                 // uniform exit, before any barrier
    const int n0 = blockIdx.y * 64;

    __shared__ char lds[65536];          // 2 x (A 16KB + B 16KB); reused fp32

    const int tid  = threadIdx.x;
    const int lane = tid & 63;
    const int w    = tid >> 6;           // wave id = k-slice id

    // ---- staging source pointers (4 issues each for A and B) ----
    const ushort* a_src[4];
    const ushort* b_src[4];
#pragma unroll
    for (int i = 0; i < 4; ++i) {
        int q   = w * 256 + i * 64 + lane;    // chunk-linear 0..1023
        int row = q >> 4;                      // 0..63
        int c   = (q & 15) ^ (row & 7);        // logical 16B k-chunk
        int ar  = m0 + row; if (ar >= M) ar = M - 1;   // clamp (junk rows masked at store)
        a_src[i] = Xb + (size_t)ar * DM + c * 8;
        b_src[i] = Wb + (size_t)(n0 + row) * DM + c * 8;
    }

#define STAGE(buf, k0) do {                                                          \
    char* _base = lds + (buf) * 32768 + w * 4096;                                    \
    _Pragma("unroll")                                                                \
    for (int _i = 0; _i < 4; ++_i) {                                                 \
        __builtin_amdgcn_global_load_lds(                                            \
            (const __attribute__((address_space(1))) unsigned*)(a_src[_i] + (k0)),   \
            (__attribute__((address_space(3))) unsigned*)(_base + _i * 1024),        \
            16, 0, 0);                                                               \
        __builtin_amdgcn_global_load_lds(                                            \
            (const __attribute__((address_space(1))) unsigned*)(b_src[_i] + (k0)),   \
            (__attribute__((address_space(3))) unsigned*)(_base + 16384 + _i * 1024),\
            16, 0, 0);                                                               \
    }                                                                                \
} while (0)

    // ---- fragment read byte-offsets (within A / B region) ----
    int aoff[4], boff[4];
#pragma unroll
    for (int f = 0; f < 4; ++f) {
        int row = f * 16 + (lane & 15);
        int c   = w * 4 + (lane >> 4);         // this wave's k window
        int cp  = c ^ (row & 7);
        aoff[f] = row * 256 + cp * 16;
        boff[f] = row * 256 + cp * 16;
    }

    f32x4 acc[4][4] = {};

    STAGE(0, 0);                               // prologue
#pragma unroll
    for (int t = 0; t < 8; ++t) {
        const int cur = t & 1;
        if (t < 7) {
            STAGE(cur ^ 1, (t + 1) * 128);
            asm volatile("s_waitcnt vmcnt(8)" ::: "memory");   // buf[cur] ready (mine)
        } else {
            asm volatile("s_waitcnt vmcnt(0)" ::: "memory");
        }
        __builtin_amdgcn_s_barrier();                          // buf[cur] ready (all)

        const char* A = lds + cur * 32768;
        const char* B = A + 16384;
        bf16x8 af[4], bfr[4];
#pragma unroll
        for (int i = 0; i < 4; ++i) af[i]  = *(const bf16x8*)(A + aoff[i]);
#pragma unroll
        for (int j = 0; j < 4; ++j) bfr[j] = *(const bf16x8*)(B + boff[j]);
#pragma unroll
        for (int i = 0; i < 4; ++i)
#pragma unroll
            for (int j = 0; j < 4; ++j)
                acc[i][j] = __builtin_amdgcn_mfma_f32_16x16x32_bf16(af[i], bfr[j], acc[i][j], 0, 0, 0);

        asm volatile("s_waitcnt lgkmcnt(0)" ::: "memory");     // my reads done
        __builtin_amdgcn_s_barrier();                          // all reads done -> next STAGE safe
    }

    // ---- 4-way partial combine via LDS (reuse staging buffer) ----
    // write: wave region w*16KB; lane 256B; frag F at swizzled 16B slot
#pragma unroll
    for (int fm = 0; fm < 4; ++fm)
#pragma unroll
        for (int fn = 0; fn < 4; ++fn) {
            int F = fm * 4 + fn;
            *(f32x4*)(lds + w * 16384 + lane * 256 + ((F ^ (lane & 15)) << 4)) = acc[fm][fn];
        }
    __syncthreads();

    // read: wave w combines frag row-band fm=w across all 4 source waves
#pragma unroll
    for (int fn = 0; fn < 4; ++fn) {
        int F = w * 4 + fn;
        f32x4 s = {0.f, 0.f, 0.f, 0.f};
#pragma unroll
        for (int sw = 0; sw < 4; ++sw)
            s += *(const f32x4*)(lds + sw * 16384 + lane * 256 + ((F ^ (lane & 15)) << 4));
        int n  = n0 + fn * 16 + (lane & 15);
        int mb = m0 + w * 16 + (lane >> 4) * 4;   // C/D: col=lane&15, row=(lane>>4)*4+r [m89]
#pragma unroll
        for (int r = 0; r < 4; ++r)
            if (mb + r < M) Tb[(size_t)(mb + r) * DM + n] = f2bf(s[r]);
    }
#undef STAGE
}

// ---------------------------------------------------------------------------
// epilogue: out[r] = x[s] + cnt[s-1] * Tb[inv[s-1]]
// ---------------------------------------------------------------------------
__global__ __launch_bounds__(256) void out_kernel(const float* __restrict__ X,
                                                  const ushort* __restrict__ Tb,
                                                  const int* __restrict__ sav,
                                                  const int* __restrict__ cnt,
                                                  const int* __restrict__ inv,
                                                  float* __restrict__ out) {
    int r = blockIdx.x;
    int d = threadIdx.x;                 // float4 lane, 0..255
    int s = sav[r];
    const float4* xr = (const float4*)(X + (size_t)s * DM);
    float4 v = xr[d];
    if (s > 0) {
        int t = s - 1;
        int c = cnt[t];
        if (c > 0) {
            float fc = (float)c;
            const ushort4* tr = (const ushort4*)(Tb + (size_t)inv[t] * DM);
            ushort4 wv = tr[d];
            v.x += fc * bf2f(wv.x); v.y += fc * bf2f(wv.y);
            v.z += fc * bf2f(wv.z); v.w += fc * bf2f(wv.w);
        }
    }
    ((float4*)out)[(size_t)r * (DM / 4) + d] = v;
}

// ---------------------------------------------------------------------------
extern "C" void kernel_launch(void* const* d_in, const int* in_sizes, int n_in,
                              void* d_out, int out_size, void* d_ws, size_t ws_size,
                              hipStream_t stream) {
    const float* X   = (const float*)d_in[0];
    const float* W   = (const float*)d_in[1];
    const int*   sav = (const int*)d_in[2];   // ids_to_save
    const int*   red = (const int*)d_in[3];   // ids_to_reduce
    float* out = (float*)d_out;

    char* ws = (char*)d_ws;
    int* counter = (int*)ws;                  // 64 ints
    int* cnt  = counter + 64;                 // 32768
    int* need = cnt + NTOK;                   // 32768
    int* inv  = need + NTOK;                  // 32768
    int* list = inv + NTOK;                   // 16384  (ends < 512 KB)
    ushort* Wb = (ushort*)(ws + (1 << 19));   // 2 MB bf16 W
    ushort* Xb = (ushort*)(ws + (4 << 20));   // 32 MB bf16 compacted X rows
    ushort* Tb = (ushort*)(ws + (36u << 20)); // 32 MB bf16 T

    setup_kernel<<<DM * DM / 4 / 256, 256, 0, stream>>>(W, Wb, cnt, need, counter);
    prep_kernel<<<NRED / 256, 256, 0, stream>>>(red, sav, cnt, need);
    compact_kernel<<<NTOK / 256, 256, 0, stream>>>(cnt, need, inv, list, counter);
    convx_kernel<<<2048, 256, 0, stream>>>(X, list, counter, Xb);

    dim3 ggrid(MMAX / 64, DM / 64);           // x = m-blocks (256, early-exit), y = n (16)
    gemm_kernel<<<ggrid, 256, 0, stream>>>(Xb, Wb, counter, Tb);

    out_kernel<<<NSAVE, 256, 0, stream>>>(X, Tb, sav, cnt, inv, out);
}